// Round 1
// baseline (26.382 us; speedup 1.0000x reference)
//
#include <hip/hip_runtime.h>

// ROI max-pool: [N=512, C=256, H=14, W=14] fp32 -> [N, C, 7, 7] fp32
// Exact non-overlapping 2x2 max windows (H%OUT==0). Memory-bound:
// each input element read exactly once (~103 MB in + ~26 MB out).

__global__ void ROIPooling_86466281603470_kernel(const float* __restrict__ in,
                                                 float* __restrict__ out,
                                                 int n_out) {
    int idx = blockIdx.x * blockDim.x + threadIdx.x;
    int stride = gridDim.x * blockDim.x;
    for (; idx < n_out; idx += stride) {
        int plane = idx / 49;            // (n*C + c)
        int rem   = idx - plane * 49;
        int i     = rem / 7;             // output row
        int j     = rem - i * 7;         // output col
        // input plane base: plane*196 floats; window rows 2i and 2i+1 (14 floats each)
        const float* base = in + (size_t)plane * 196 + i * 28;
        // byte offsets are multiples of 8 -> aligned float2 loads
        float2 a = *reinterpret_cast<const float2*>(base + 2 * j);
        float2 b = *reinterpret_cast<const float2*>(base + 14 + 2 * j);
        out[idx] = fmaxf(fmaxf(a.x, a.y), fmaxf(b.x, b.y));
    }
}

extern "C" void kernel_launch(void* const* d_in, const int* in_sizes, int n_in,
                              void* d_out, int out_size, void* d_ws, size_t ws_size,
                              hipStream_t stream) {
    const float* in = (const float*)d_in[0];
    float* out = (float*)d_out;
    int n_out = out_size;                 // 512*256*7*7 = 6,422,528
    int block = 256;
    int grid = (n_out + block - 1) / block;
    if (grid > 2048) grid = 2048;         // grid-stride the rest
    ROIPooling_86466281603470_kernel<<<grid, block, 0, stream>>>(in, out, n_out);
}

// Round 2
// 24.718 us; speedup vs baseline: 1.0673x; 1.0673x over previous
//
#include <hip/hip_runtime.h>

// ROI max-pool: [512*256 planes, 14x14] fp32 -> [planes, 7x7] fp32.
// Exact 2x2 non-overlapping max windows. Memory-bound (~103 MB in, ~26 MB out).
//
// Strategy: LDS-staged. Each block stages PLANES_PER_BLOCK=16 whole planes
// (16*196 floats = 12.25 KB) via fully-coalesced float4 loads (16 B/lane),
// then computes 16*49 = 784 outputs from LDS (float2 reads, <=2-way bank
// aliasing which is free) with contiguous dword stores.

#define PPB   16          // planes per block
#define BLOCK 256

__global__ __launch_bounds__(BLOCK)
void ROIPooling_86466281603470_kernel(const float* __restrict__ in,
                                      float* __restrict__ out) {
    __shared__ float lds[PPB * 196];   // 12544 B

    const int pb = blockIdx.x * PPB;   // first plane handled by this block

    // ---- stage: 16 planes = 784 float4, perfectly coalesced ----
    const float4* __restrict__ in4 =
        reinterpret_cast<const float4*>(in + (size_t)pb * 196);
    float4* lds4 = reinterpret_cast<float4*>(lds);
    #pragma unroll
    for (int v = threadIdx.x; v < PPB * 49; v += BLOCK) {
        lds4[v] = in4[v];
    }
    __syncthreads();

    // ---- compute: 784 outputs, contiguous stores ----
    float* __restrict__ outb = out + (size_t)pb * 49;
    #pragma unroll
    for (int o = threadIdx.x; o < PPB * 49; o += BLOCK) {
        int p   = o / 49;              // plane within block (magic-mul)
        int rem = o - p * 49;
        int i   = rem / 7;             // output row
        int j   = rem - i * 7;         // output col
        const float* base = lds + p * 196 + i * 28;   // row 2i of the plane
        float2 a = *reinterpret_cast<const float2*>(base + 2 * j);        // row 2i
        float2 b = *reinterpret_cast<const float2*>(base + 14 + 2 * j);   // row 2i+1
        outb[o] = fmaxf(fmaxf(a.x, a.y), fmaxf(b.x, b.y));
    }
}

extern "C" void kernel_launch(void* const* d_in, const int* in_sizes, int n_in,
                              void* d_out, int out_size, void* d_ws, size_t ws_size,
                              hipStream_t stream) {
    const float* in = (const float*)d_in[0];
    float* out = (float*)d_out;
    int n_planes = out_size / 49;            // 512*256 = 131072, divisible by PPB
    int grid = n_planes / PPB;               // 8192 blocks
    ROIPooling_86466281603470_kernel<<<grid, BLOCK, 0, stream>>>(in, out);
}